// Round 9
// baseline (502.120 us; speedup 1.0000x reference)
//
#include <hip/hip_runtime.h>
#include <hip/hip_fp16.h>
#include <math.h>

// Problem constants
#define V    20000
#define SCV  4000
#define LL   15
#define OUTN (16384 * 128)   // B*S*D

#define LEAF_BIT 0x40000000
#define REF_MASK 0x3FFFFFFF
#define ROOT_BIT 0x20000000   // on E.x only: node is a tree root (write hInt only)
#define SLOT_MASK 0x1FFFFFFF
#define DUMMY_SLOT 89999     // total internal nodes ~80k < 89999

// ---- workspace layout (bytes) ----
#define OFF_COUNTS 0
#define OFF_ROOT   128
#define OFF_LISTS  80384
#define OFF_LEAFC  5968384
#define OFF_LEAFHH 8016384
#define OFF_EMBT   9040384     // fp16 [4000][128][8] = 8.192 MB
#define OFF_WT     19280384
#define OFF_BIAS   19608064
#define OFF_HINT   19610624
#define OFF_CINT   65690624
#define OFF_HH     111770624
#define OFF_USED   134810624

// per-height lists: h1@0 (cap 80000), h2@80000, h3@120000, h4@160000,
// h5@180000, h6@200000, h7@220000
__device__ __constant__ int d_listOff[8] = {0, 0, 80000, 120000, 160000, 180000, 200000, 220000};

#define MT 128

typedef _Float16 f16x8 __attribute__((ext_vector_type(8)));
typedef float    f32x4 __attribute__((ext_vector_type(4)));

__device__ __forceinline__ float sigm(float x) { return 1.0f / (1.0f + expf(-x)); }

// ---------------- prep: leaf states + embT + WT transpose + biasSum + mark ----------
// grid 1024 x 256. Blocks 0..39 also do one 64x64 WT tile; block 41 does biasSum.
__global__ void prep_kernel(const int* __restrict__ input,
                            const float* __restrict__ emb,
                            const float* __restrict__ Wl, const float* __restrict__ Wlb,
                            const float* __restrict__ Wr, const float* __restrict__ Wrb,
                            float* __restrict__ leafC, __half* __restrict__ leafHh,
                            __half* __restrict__ embT,
                            __half* __restrict__ WT, float* __restrict__ biasSum,
                            unsigned char* __restrict__ used) {
    __shared__ float T[64][65];
    int t = threadIdx.x, bid = blockIdx.x;
    // leaf (h,c) per sub-char id: 2 rows per block-iter
    for (int r = bid * 2 + (t >> 7); r < SCV; r += gridDim.x * 2) {
        int i = t & 127;
        const float* e = emb + r * 640;
        float c = sigm(e[i]) * tanhf(e[512 + i]);
        float h = sigm(e[384 + i]) * tanhf(c);
        leafC[r * 128 + i] = c;
        leafHh[r * 128 + i] = __float2half(h);
    }
    // embT[id][d][0..4] = fp16(emb[id][p*128+d]), [5..7]=0  (one 16B row per (id,d))
    for (int idx = bid * 256 + t; idx < SCV * 128; idx += gridDim.x * 256) {
        int id = idx >> 7, dd = idx & 127;
        const float* e = emb + id * 640 + dd;
        __half v[8];
#pragma unroll
        for (int p = 0; p < 5; ++p) v[p] = __float2half(e[p * 128]);
        v[5] = __float2half(0.f); v[6] = v[5]; v[7] = v[5];
        *(uint4*)(embT + (size_t)idx * 8) = *(const uint4*)v;
    }
    // mark used tokens
    for (int i = bid * 256 + t; i < 16384; i += gridDim.x * 256)
        used[input[i]] = 1;
    // bias sum
    if (bid == 41)
        for (int i = t; i < 640; i += 256) biasSum[i] = Wlb[i] + Wrb[i];
    // WT[n][k] = fp16([Wl;Wr][k][n]); 40 tiles of 64x64, one per block 0..39
    if (bid < 40) {
        int kb = (bid & 3) * 64, nb = (bid >> 2) * 64;
        int tx = t & 63, ty = t >> 6;            // 256 threads: ty 0..3
        for (int kk = ty; kk < 64; kk += 4) {
            int k = kb + kk;
            const float* Wsrc = (k < 128) ? (Wl + k * 640) : (Wr + (k - 128) * 640);
            T[kk][tx] = Wsrc[nb + tx];
        }
        __syncthreads();
        for (int nn = ty; nn < 64; nn += 4)
            WT[(nb + nn) * 256 + kb + tx] = __float2half(T[tx][nn]);
    }
}

// ---------------- metadata: heights, compact slots, per-height lists ----------------
__global__ void meta_kernel(const int* __restrict__ node_ids,
                            const int* __restrict__ left,
                            const int* __restrict__ right,
                            const int* __restrict__ last,
                            const unsigned char* __restrict__ used,
                            int* __restrict__ counts,
                            int* __restrict__ rootSlot,
                            int4* __restrict__ lists) {
    __shared__ int  sHei[MT][17];
    __shared__ int  sRef[MT][17];
    __shared__ int4 ebuf[MT][7];
    __shared__ int  ebin[MT][7];
    __shared__ int  locCnt[8];
    __shared__ int  basePos[8];
    __shared__ int  scanBuf[MT];
    __shared__ int  blockBase;

    int tid = threadIdx.x;
    if (tid < 8) locCnt[tid] = 0;
    __syncthreads();

    int v = blockIdx.x * MT + tid;
    int nInt = 0;
    if (v < V && used[v]) {
        int l15[LL], r15[LL], id15[LL];
#pragma unroll
        for (int j = 0; j < LL; ++j) {
            l15[j]  = left[v * LL + j];
            r15[j]  = right[v * LL + j];
            id15[j] = node_ids[v * LL + j];
        }
        int lastv = last[v];
#pragma unroll
        for (int j = 0; j < LL; ++j) {
            if (j <= lastv) {
                int l = l15[j];
                if (l < 0) {
                    sHei[tid][j] = 0;
                    sRef[tid][j] = LEAF_BIT | id15[j];
                } else {
                    int r = r15[j];
                    int hl = sHei[tid][l], hr = sHei[tid][r];
                    int hh = 1 + (hl > hr ? hl : hr);
                    sHei[tid][j] = hh;
                    int pos = atomicAdd(&locCnt[hh], 1);
                    int flag = (j == lastv) ? ROOT_BIT : 0;
                    ebuf[tid][nInt] = make_int4(nInt | flag, id15[j], sRef[tid][l], sRef[tid][r]);
                    ebin[tid][nInt] = (hh << 16) | pos;
                    sRef[tid][j] = nInt;
                    ++nInt;
                }
            }
        }
    }
    // block-level inclusive scan of nInt -> compact slot bases
    scanBuf[tid] = nInt;
    __syncthreads();
    for (int d = 1; d < MT; d <<= 1) {
        int val = (tid >= d) ? scanBuf[tid - d] : 0;
        __syncthreads();
        scanBuf[tid] += val;
        __syncthreads();
    }
    if (tid == 0) blockBase = atomicAdd(&counts[31], scanBuf[MT - 1]);
    if (tid < 8) {
        int c = locCnt[tid];
        basePos[tid] = c ? atomicAdd(&counts[tid], c) : 0;
    }
    __syncthreads();
    int treeBase = blockBase + scanBuf[tid] - nInt;
    if (v < V && nInt > 0) rootSlot[v] = treeBase + nInt - 1;
    for (int e = 0; e < nInt; ++e) {
        int4 E  = ebuf[tid][e];
        int md  = ebin[tid][e];
        int hh  = md >> 16, pos = md & 0xFFFF;
        E.x += treeBase;                                   // ROOT_BIT preserved
        E.z = (E.z & LEAF_BIT) ? E.z : (E.z + treeBase);
        E.w = (E.w & LEAF_BIT) ? E.w : (E.w + treeBase);
        lists[d_listOff[hh] + basePos[hh] + pos] = E;
    }
}

// ---------------- MFMA round: all heights 1..7, unified K=256 ----------------
// No-LDS direct version, 16 nodes/group, one dim-column per wave:
//   8 waves; wave w owns cols {128p + 16w + ln15, p=0..4} = the 5 gates of
//   dim d=16w+ln15 for the group's 16 nodes -> acc[5] (20 regs), full
//   in-register LSTM epilogue.
//   A fragments loaded per-lane DIRECTLY from global (lane ln15 = node
//   base+ln15's children rows); 8 waves' redundant A reads hit L1/L2 because
//   the per-group __syncthreads() keeps waves in a tight window.
//   That barrier is ALSO what keeps each node's 512B output row (8 waves x
//   64B pieces) temporally clustered -> no partial-line writeback
//   amplification (round-6 lesson: no barrier => WRITE 12.5 -> 160 MB).
//   No LDS phases, one load-issue region per group -> max MLP (round-6
//   evidence: this access pattern sustains 2.7 TB/s vs 0.73 with phases).
__launch_bounds__(512, 4)
__global__ void round_mfma(const int4* __restrict__ list, const int* __restrict__ cntPtr,
                           const __half* __restrict__ embT, const __half* __restrict__ WT,
                           const float* __restrict__ biasSum,
                           const __half* __restrict__ leafHh, const float* __restrict__ leafC,
                           float* __restrict__ hInt, float* __restrict__ cInt,
                           __half* __restrict__ hH) {
    int cnt = *cntPtr;
    int nGroups = (cnt + 15) >> 4;
    int t = threadIdx.x;
    int lane = t & 63, wave = t >> 6;        // 8 waves
    int ln15 = lane & 15, quad = lane >> 4;
    int d = 16 * wave + ln15;
    float bs[5];
#pragma unroll
    for (int p = 0; p < 5; ++p) bs[p] = biasSum[p * 128 + d];
    const __half* wbase = WT + d * 256 + quad * 8;

    for (int grp = blockIdx.x; grp < nGroups; grp += gridDim.x) {
        int base = grp * 16;
        // ---- A-row child pointers for this lane's MFMA row (node base+ln15) ----
        int rz = LEAF_BIT, rw = LEAF_BIT;
        if (base + ln15 < cnt) { int4 E = list[base + ln15]; rz = E.z; rw = E.w; }
        const __half* aPL = ((rz & LEAF_BIT) ? leafHh : hH) + (rz & REF_MASK) * 128;
        const __half* aPR = ((rw & LEAF_BIT) ? leafHh : hH) + (rw & REF_MASK) * 128;
        // ---- meta for this thread's 4 epilogue nodes (quad*4+r), kept in regs ----
        int4 Er[4];
#pragma unroll
        for (int r = 0; r < 4; ++r) {
            int m = quad * 4 + r;
            if (base + m < cnt) Er[r] = list[base + m];
            else { Er[r].x = DUMMY_SLOT; Er[r].y = 0; Er[r].z = LEAF_BIT; Er[r].w = LEAF_BIT; }
        }
        // ---- C init from fp16 padded table: one 16B load per node ----
        f32x4 acc[5];
#pragma unroll
        for (int r = 0; r < 4; ++r) {
            f16x8 ev = *(const f16x8*)((const void*)(embT + ((size_t)Er[r].y * 128 + d) * 8));
#pragma unroll
            for (int p = 0; p < 5; ++p)
                acc[p][r] = (float)ev[p] + bs[p];
        }
        // ---- K loop: 8 steps of 32; A direct from global, B from L2-hot WT ----
#pragma unroll
        for (int kb = 0; kb < 8; ++kb) {
            const __half* aSrc = (kb < 4) ? aPL : aPR;
            f16x8 af = *(const f16x8*)((const void*)(aSrc + (kb & 3) * 32 + quad * 8));
#pragma unroll
            for (int p = 0; p < 5; ++p) {
                f16x8 bf = *(const f16x8*)((const void*)(wbase + p * 32768 + kb * 32));
                acc[p] = __builtin_amdgcn_mfma_f32_16x16x32_f16(af, bf, acc[p], 0, 0, 0);
            }
        }
        // ---- in-register LSTM epilogue: dim d, gates = p ----
#pragma unroll
        for (int r = 0; r < 4; ++r) {
            int4 E = Er[r];
            float ig = acc[0][r], lfg = acc[1][r], rfg = acc[2][r];
            float og = acc[3][r], ug = acc[4][r];
            float cl = ((E.z & LEAF_BIT) ? leafC : cInt)[(E.z & REF_MASK) * 128 + d];
            float cr = ((E.w & LEAF_BIT) ? leafC : cInt)[(E.w & REF_MASK) * 128 + d];
            float cc = sigm(ig) * tanhf(ug) + sigm(lfg) * cl + sigm(rfg) * cr;
            float hh2 = sigm(og) * tanhf(cc);
            int slot = E.x & SLOT_MASK;
            if (E.x & ROOT_BIT) {
                hInt[slot * 128 + d] = hh2;      // root: only f32 h is read (gather)
            } else {
                cInt[slot * 128 + d] = cc;       // non-root: c + fp16 h are read
                hH[slot * 128 + d] = __float2half(hh2);
            }
        }
        __syncthreads();   // cluster the 8 waves' writes in time (round-6 lesson)
    }
}

// ---------------- final gather: out[b,s,:] = h_root[input[b,s]] ----------------
__global__ void gather_kernel(const int* __restrict__ input,
                              const int* __restrict__ rootSlot,
                              const float* __restrict__ hInt,
                              float4* __restrict__ out) {
    int idx = blockIdx.x * 256 + threadIdx.x;   // < OUTN/4
    int token = input[idx >> 5];
    int d = idx & 31;
    out[idx] = ((const float4*)hInt)[rootSlot[token] * 32 + d];
}

extern "C" void kernel_launch(void* const* d_in, const int* in_sizes, int n_in,
                              void* d_out, int out_size, void* d_ws, size_t ws_size,
                              hipStream_t stream) {
    const int*   input    = (const int*)d_in[0];
    const int*   node_ids = (const int*)d_in[1];
    const int*   left     = (const int*)d_in[2];
    const int*   right    = (const int*)d_in[3];
    const int*   last     = (const int*)d_in[4];
    const float* emb      = (const float*)d_in[5];
    const float* Wl       = (const float*)d_in[6];
    const float* Wlb      = (const float*)d_in[7];
    const float* Wr       = (const float*)d_in[8];
    const float* Wrb      = (const float*)d_in[9];
    float* out = (float*)d_out;

    char* ws = (char*)d_ws;
    int*    counts   = (int*)(ws + OFF_COUNTS);
    int*    rootSlot = (int*)(ws + OFF_ROOT);
    int4*   lists    = (int4*)(ws + OFF_LISTS);
    float*  leafC    = (float*)(ws + OFF_LEAFC);
    __half* leafHh   = (__half*)(ws + OFF_LEAFHH);
    __half* embT     = (__half*)(ws + OFF_EMBT);
    __half* WT       = (__half*)(ws + OFF_WT);
    float*  biasSum  = (float*)(ws + OFF_BIAS);
    float*  hInt     = (float*)(ws + OFF_HINT);
    float*  cInt     = (float*)(ws + OFF_CINT);
    __half* hH       = (__half*)(ws + OFF_HH);
    unsigned char* usedp = (unsigned char*)(ws + OFF_USED);

    (void)hipMemsetAsync(counts, 0, 128, stream);
    (void)hipMemsetAsync(usedp, 0, V, stream);

    prep_kernel<<<1024, 256, 0, stream>>>(input, emb, Wl, Wlb, Wr, Wrb,
                                          leafC, leafHh, embT, WT, biasSum, usedp);
    meta_kernel<<<(V + MT - 1) / MT, MT, 0, stream>>>(node_ids, left, right, last, usedp,
                                                      counts, rootSlot, lists);

    static const int h_listOff[8] = {0, 0, 80000, 120000, 160000, 180000, 200000, 220000};
    static const int h_grid[8]    = {0, 1024, 768, 384, 192, 64, 32, 16};
    for (int h = 1; h <= 7; ++h) {
        round_mfma<<<h_grid[h], 512, 0, stream>>>(
            lists + h_listOff[h], counts + h,
            embT, WT, biasSum, leafHh, leafC, hInt, cInt, hH);
    }

    gather_kernel<<<OUTN / 4 / 256, 256, 0, stream>>>(input, rootSlot, hInt, (float4*)out);
}